// Round 14
// baseline (41.024 us; speedup 1.0000x reference)
//
#include <hip/hip_runtime.h>

#define T_FRAMES 256
#define D_IN 80
#define CCH 256
#define CCEP 222
#define FFT_N 1024
#define HOP 256
#define WINL 512
#define PF_KT 128
#define ZLEN 65536

__device__ __forceinline__ unsigned br10(unsigned x) { return __brev(x) >> 22; }

// =============== conv inner loop (256 thr: c = tid, 8 frames/block) ===============
// wlds4[j4*256+c]: 12 f4 per c (16 cin x 3 taps). inlds4[row*4+cg]: 10 rows x 4 f4.
__device__ __forceinline__ void conv_inner8(const float4* __restrict__ wlds4,
                                            const float4* __restrict__ inlds4,
                                            int c, float* __restrict__ acc) {
  #pragma unroll
  for (int cg = 0; cg < 4; ++cg) {
    float4 w0 = wlds4[(cg * 3 + 0) * 256 + c];
    float4 w1v = wlds4[(cg * 3 + 1) * 256 + c];
    float4 w2v = wlds4[(cg * 3 + 2) * 256 + c];
    float4 xr[10];
    #pragma unroll
    for (int r = 0; r < 10; ++r) xr[r] = inlds4[r * 4 + cg];
    #pragma unroll
    for (int j = 0; j < 8; ++j) {
      float4 xa = xr[j], xb = xr[j + 1], xc = xr[j + 2];
      acc[j] += xa.x * w0.x  + xb.x * w0.y  + xc.x * w0.z
              + xa.y * w0.w  + xb.y * w1v.x + xc.y * w1v.y
              + xa.z * w1v.z + xb.z * w1v.w + xc.z * w2v.x
              + xa.w * w2v.y + xb.w * w2v.z + xc.w * w2v.w;
    }
  }
}

// ---- K1: conv1 partials. grid (5 kc, 32 g), 256 thr, 2 blocks/CU ----
__global__ __launch_bounds__(256, 2) void conv1_k(const float* __restrict__ x, const float* __restrict__ w1,
                                                  float* __restrict__ h1p) {
  __shared__ float4 wlds4[12 * 256];  // 48 KB
  __shared__ float4 inlds4[10 * 4];
  const int kc = blockIdx.x, g = blockIdx.y, tid = threadIdx.x;
  const int t0 = g << 3;
  const float4* w14 = (const float4*)w1;  // row = 60 f4
  const float4* x4 = (const float4*)x;    // row = 20 f4
  #pragma unroll
  for (int it = 0; it < 12; ++it) {
    int idx = it * 256 + tid, cc = idx & 255, j4 = idx >> 8;
    wlds4[j4 * 256 + cc] = w14[cc * 60 + kc * 12 + j4];
  }
  if (tid < 40) {
    int r = tid >> 2, cg = tid & 3, tt = t0 - 1 + r;
    inlds4[tid] = (tt >= 0 && tt < T_FRAMES) ? x4[tt * 20 + kc * 4 + cg] : make_float4(0.f, 0.f, 0.f, 0.f);
  }
  __syncthreads();
  const int c = tid;
  float acc[8] = {0.f, 0.f, 0.f, 0.f, 0.f, 0.f, 0.f, 0.f};
  conv_inner8(wlds4, inlds4, c, acc);
  const int ob = kc << 8;
  #pragma unroll
  for (int j = 0; j < 8; ++j) h1p[(ob + t0 + j) * CCH + c] = acc[j];
}

// ---- K2: conv2 partials. grid (16 kc, 32 g). input h1 = relu(b1 + sum5 h1p) ----
__global__ __launch_bounds__(256, 2) void conv2_k(const float* __restrict__ h1p, const float* __restrict__ b1,
                                                  const float* __restrict__ w2, float* __restrict__ h2p) {
  __shared__ float4 wlds4[12 * 256];
  __shared__ float4 inlds4[10 * 4];
  const int kc = blockIdx.x, g = blockIdx.y, tid = threadIdx.x;
  const int t0 = g << 3;
  const float4* w24 = (const float4*)w2;    // row = 192 f4
  const float4* h1p4 = (const float4*)h1p;  // row = 64 f4
  const float4* b14 = (const float4*)b1;
  #pragma unroll
  for (int it = 0; it < 12; ++it) {
    int idx = it * 256 + tid, cc = idx & 255, j4 = idx >> 8;
    wlds4[j4 * 256 + cc] = w24[cc * 192 + kc * 12 + j4];
  }
  if (tid < 40) {
    int r = tid >> 2, cg = tid & 3, tt = t0 - 1 + r;
    float4 s = make_float4(0.f, 0.f, 0.f, 0.f);
    if (tt >= 0 && tt < T_FRAMES) {
      s = b14[kc * 4 + cg];
      #pragma unroll
      for (int p = 0; p < 5; ++p) {
        float4 v = h1p4[((p << 8) + tt) * 64 + kc * 4 + cg];
        s.x += v.x; s.y += v.y; s.z += v.z; s.w += v.w;
      }
      s.x = fmaxf(s.x, 0.f); s.y = fmaxf(s.y, 0.f); s.z = fmaxf(s.z, 0.f); s.w = fmaxf(s.w, 0.f);
    }
    inlds4[tid] = s;
  }
  __syncthreads();
  const int c = tid;
  float acc[8] = {0.f, 0.f, 0.f, 0.f, 0.f, 0.f, 0.f, 0.f};
  conv_inner8(wlds4, inlds4, c, acc);
  const int ob = kc << 8;
  #pragma unroll
  for (int j = 0; j < 8; ++j) h2p[(ob + t0 + j) * CCH + c] = acc[j];
}

// ---- K3: conv3 partials. grid (16 kc, 32 g). input h2 = relu(b2 + sum16 h2p).
//      Writes ccp TRANSPOSED: ccpt[(t*222 + cq)*16 + kc] for vectorized sum in fftltv ----
__global__ __launch_bounds__(256, 2) void conv3_k(const float* __restrict__ h2p, const float* __restrict__ b2,
                                                  const float* __restrict__ w3, float* __restrict__ ccpt) {
  __shared__ float4 wlds4[12 * 256];
  __shared__ float4 inlds4[10 * 4];
  const int kc = blockIdx.x, g = blockIdx.y, tid = threadIdx.x;
  const int t0 = g << 3;
  const float4* w34 = (const float4*)w3;    // row = 192 f4
  const float4* h2p4 = (const float4*)h2p;  // row = 64 f4
  const float4* b24 = (const float4*)b2;
  #pragma unroll
  for (int it = 0; it < 12; ++it) {
    int idx = it * 256 + tid, cc = idx & 255, j4 = idx >> 8;
    if (cc < CCEP) wlds4[j4 * 256 + cc] = w34[cc * 192 + kc * 12 + j4];
  }
  if (tid < 40) {
    int r = tid >> 2, cg = tid & 3, tt = t0 - 1 + r;
    float4 s = make_float4(0.f, 0.f, 0.f, 0.f);
    if (tt >= 0 && tt < T_FRAMES) {
      s = b24[kc * 4 + cg];
      #pragma unroll
      for (int p = 0; p < 16; ++p) {
        float4 v = h2p4[((p << 8) + tt) * 64 + kc * 4 + cg];
        s.x += v.x; s.y += v.y; s.z += v.z; s.w += v.w;
      }
      s.x = fmaxf(s.x, 0.f); s.y = fmaxf(s.y, 0.f); s.z = fmaxf(s.z, 0.f); s.w = fmaxf(s.w, 0.f);
    }
    inlds4[tid] = s;
  }
  __syncthreads();
  const int c = tid;
  if (c < CCEP) {
    float acc[8] = {0.f, 0.f, 0.f, 0.f, 0.f, 0.f, 0.f, 0.f};
    conv_inner8(wlds4, inlds4, c, acc);
    #pragma unroll
    for (int j = 0; j < 8; ++j) ccpt[((t0 + j) * CCEP + c) * 16 + kc] = acc[j];
  }
}

// ---- K4: fused spectral kernel (correlation theorem); ccpt sum via 4x float4 ----
__global__ __launch_bounds__(512) void fftltv_k(const float* __restrict__ ccpt, const float* __restrict__ b3,
                                                const float* __restrict__ quef, const float* __restrict__ z,
                                                const float* __restrict__ win, float* __restrict__ outw) {
  __shared__ float2 U[FFT_N];
  int t = blockIdx.x, tid = threadIdx.x;
  for (int i = tid; i < FFT_N; i += 512) {
    unsigned q = br10((unsigned)i);
    float a = 0.f, bv = 0.f;
    if (q >= 401u && q < 623u) {
      int cq = (int)(q - 401u);
      const float4* c4 = (const float4*)(ccpt + ((size_t)t * CCEP + cq) * 16);
      float4 s0 = c4[0], s1 = c4[1], s2 = c4[2], s3 = c4[3];
      float s = b3[cq] + s0.x + s0.y + s0.z + s0.w + s1.x + s1.y + s1.z + s1.w
                        + s2.x + s2.y + s2.z + s2.w + s3.x + s3.y + s3.z + s3.w;
      a = s / quef[cq];
    }
    if (q < 512u) {
      int idx = t * HOP + (int)q - 255;
      bv = (idx >= 0 && idx < ZLEN) ? z[idx] : 0.f;
    }
    U[i] = make_float2(a, bv);
  }
  __syncthreads();
  #pragma unroll
  for (int s = 1; s <= 10; ++s) {
    int half = 1 << (s - 1);
    int pos = tid & (half - 1);
    int i1 = ((tid >> (s - 1)) << s) + pos;
    int i2 = i1 + half;
    float ang = (-6.283185307179586f / (float)(1 << s)) * (float)pos;
    float sn, cs; __sincosf(ang, &sn, &cs);
    float2 v2 = U[i2], v1 = U[i1];
    float tr = cs * v2.x - sn * v2.y;
    float ti = cs * v2.y + sn * v2.x;
    U[i1] = make_float2(v1.x + tr, v1.y + ti);
    U[i2] = make_float2(v1.x - tr, v1.y - ti);
    __syncthreads();
  }
  {
    int j = tid;
    int mj = (FFT_N - j) & (FFT_N - 1);
    float2 Uj = U[j], Um = U[mj];
    float2 U5j = make_float2(0.f, 0.f);
    if (tid == 0) U5j = U[512];
    auto pcalc = [](float2 Uj, float2 Um) -> float2 {
      float Ar = 0.5f * (Uj.x + Um.x);
      float Ai = 0.5f * (Uj.y - Um.y);
      float Bx = 0.5f * (Uj.y + Um.y);
      float By = 0.5f * (Um.x - Uj.x);
      float mag = __expf(0.23025850929940457f * Ar);
      float sn, cs; __sincosf(Ai, &sn, &cs);
      float SPx = mag * cs, SPy = mag * sn;
      return make_float2(Bx * SPx + By * SPy, Bx * SPy - By * SPx);
    };
    float2 Pj = pcalc(Uj, Um);
    float2 P5 = (tid == 0) ? pcalc(U5j, U5j) : make_float2(0.f, 0.f);
    __syncthreads();
    U[j] = Pj;
    if (tid == 0) U[512] = P5;
    else U[mj] = make_float2(Pj.x, -Pj.y);
  }
  __syncthreads();
  #pragma unroll
  for (int s = 10; s >= 1; --s) {
    int half = 1 << (s - 1);
    int pos = tid & (half - 1);
    int i1 = ((tid >> (s - 1)) << s) + pos;
    int i2 = i1 + half;
    float ang = (6.283185307179586f / (float)(1 << s)) * (float)pos;
    float sn, cs; __sincosf(ang, &sn, &cs);
    float2 v1 = U[i1], v2 = U[i2];
    U[i1] = make_float2(v1.x + v2.x, v1.y + v2.y);
    float dr = v1.x - v2.x, di = v1.y - v2.y;
    U[i2] = make_float2(cs * dr - sn * di, cs * di + sn * dr);
    __syncthreads();
  }
  const float inv = 1.0f / (float)FFT_N;
  for (int i = tid; i < FFT_N; i += 512) {
    unsigned m = br10((unsigned)i);
    if (m < 512u) {
      int w = 511 - (int)m;
      outw[t * WINL + w] = U[i].x * inv * win[w];
    }
  }
}

// ---- K5: overlap-add (circular roll over t) + 128-tap postfilter ----
__global__ __launch_bounds__(256) void pf_k(const float* __restrict__ outw, const float* __restrict__ pf_w,
                                            const float* __restrict__ pf_b, float* __restrict__ y) {
  __shared__ float sb[256 + PF_KT - 1];
  __shared__ float wpf[PF_KT];
  int n0 = blockIdx.x * 256;
  for (int i = threadIdx.x; i < 256 + PF_KT - 1; i += 256) {
    int m = n0 - 63 + i;
    float v = 0.f;
    if (m >= 0 && m < ZLEN) {
      int t = m >> 8, j = m & 255;
      v = outw[t * WINL + j] + outw[((t - 1) & 255) * WINL + HOP + j];
    }
    sb[i] = v;
  }
  if (threadIdx.x < PF_KT) wpf[threadIdx.x] = pf_w[threadIdx.x];
  __syncthreads();
  float acc = pf_b[0];
  #pragma unroll 8
  for (int j = 0; j < PF_KT; ++j) acc += sb[threadIdx.x + j] * wpf[j];
  y[n0 + threadIdx.x] = acc;
}

extern "C" void kernel_launch(void* const* d_in, const int* in_sizes, int n_in,
                              void* d_out, int out_size, void* d_ws, size_t ws_size,
                              hipStream_t stream) {
  const float* x    = (const float*)d_in[0];
  const float* z    = (const float*)d_in[1];
  const float* w1   = (const float*)d_in[2];
  const float* b1   = (const float*)d_in[3];
  const float* w2   = (const float*)d_in[4];
  const float* b2   = (const float*)d_in[5];
  const float* w3   = (const float*)d_in[6];
  const float* b3   = (const float*)d_in[7];
  const float* pf_w = (const float*)d_in[8];
  const float* pf_b = (const float*)d_in[9];
  const float* quef = (const float*)d_in[10];
  const float* win  = (const float*)d_in[11];
  float* out = (float*)d_out;
  float* ws  = (float*)d_ws;

  // workspace layout (floats)
  float* h1p  = ws;                 // 5*256*256  = 327680
  float* h2p  = h1p + 327680;       // 16*256*256 = 1048576
  float* ccpt = h2p + 1048576;      // 256*222*16 = 909312 (transposed)
  float* outw = ccpt + 909312;      // 256*512    = 131072

  conv1_k<<<dim3(5, 32), 256, 0, stream>>>(x, w1, h1p);
  conv2_k<<<dim3(16, 32), 256, 0, stream>>>(h1p, b1, w2, h2p);
  conv3_k<<<dim3(16, 32), 256, 0, stream>>>(h2p, b2, w3, ccpt);
  fftltv_k<<<T_FRAMES, 512, 0, stream>>>(ccpt, b3, quef, z, win, outw);
  pf_k<<<ZLEN / 256, 256, 0, stream>>>(outw, pf_w, pf_b, out);
}

// Round 15
// 39.895 us; speedup vs baseline: 1.0283x; 1.0283x over previous
//
#include <hip/hip_runtime.h>

#define T_FRAMES 256
#define D_IN 80
#define CCH 256
#define CCEP 222
#define FFT_N 1024
#define HOP 256
#define WINL 512
#define PF_KT 128
#define ZLEN 65536

__device__ __forceinline__ unsigned br10(unsigned x) { return __brev(x) >> 22; }

// =============== shared conv inner loop (512 thr: c = tid&255, fh = tid>>8, 8 frames each) ===============
__device__ __forceinline__ void conv_inner(const float4* __restrict__ wlds4,
                                           const float4* __restrict__ inlds4,
                                           int c, int fh, float* __restrict__ acc) {
  #pragma unroll
  for (int cg = 0; cg < 4; ++cg) {
    float4 w0 = wlds4[(cg * 3 + 0) * 256 + c];
    float4 w1v = wlds4[(cg * 3 + 1) * 256 + c];
    float4 w2v = wlds4[(cg * 3 + 2) * 256 + c];
    float4 xr[10];
    #pragma unroll
    for (int r = 0; r < 10; ++r) xr[r] = inlds4[(fh * 8 + r) * 4 + cg];
    #pragma unroll
    for (int j = 0; j < 8; ++j) {
      float4 xa = xr[j], xb = xr[j + 1], xc = xr[j + 2];
      acc[j] += xa.x * w0.x  + xb.x * w0.y  + xc.x * w0.z
              + xa.y * w0.w  + xb.y * w1v.x + xc.y * w1v.y
              + xa.z * w1v.z + xb.z * w1v.w + xc.z * w2v.x
              + xa.w * w2v.y + xb.w * w2v.z + xc.w * w2v.w;
    }
  }
}

// ---- K1: conv1 partials. grid (5 kc, 16 g). L1-reuse weight staging ----
__global__ __launch_bounds__(512) void conv1_k(const float* __restrict__ x, const float* __restrict__ w1,
                                               float* __restrict__ h1p) {
  __shared__ float4 wlds4[12 * 256];  // 48 KB
  __shared__ float4 inlds4[18 * 4];
  const int kc = blockIdx.x, g = blockIdx.y, tid = threadIdx.x;
  const int t0 = g << 4;
  const float4* w14 = (const float4*)w1;  // row = 60 f4
  const float4* x4 = (const float4*)x;    // row = 20 f4
  {
    const int row = tid & 255, seg = tid >> 8;
    const float4* src = w14 + row * 60 + kc * 12 + seg * 6;
    #pragma unroll
    for (int m = 0; m < 6; ++m) wlds4[(seg * 6 + m) * 256 + row] = src[m];
  }
  if (tid < 72) {
    int r = tid >> 2, cg = tid & 3, tt = t0 - 1 + r;
    inlds4[tid] = (tt >= 0 && tt < T_FRAMES) ? x4[tt * 20 + kc * 4 + cg] : make_float4(0.f, 0.f, 0.f, 0.f);
  }
  __syncthreads();
  const int c = tid & 255, fh = tid >> 8;
  float acc[8] = {0.f, 0.f, 0.f, 0.f, 0.f, 0.f, 0.f, 0.f};
  conv_inner(wlds4, inlds4, c, fh, acc);
  const int ob = kc << 8;
  #pragma unroll
  for (int j = 0; j < 8; ++j) h1p[(ob + t0 + fh * 8 + j) * CCH + c] = acc[j];
}

// ---- K2: conv2 partials. grid (16 kc, 16 g). input h1 = relu(b1 + sum5 h1p) ----
__global__ __launch_bounds__(512) void conv2_k(const float* __restrict__ h1p, const float* __restrict__ b1,
                                               const float* __restrict__ w2, float* __restrict__ h2p) {
  __shared__ float4 wlds4[12 * 256];
  __shared__ float4 inlds4[18 * 4];
  const int kc = blockIdx.x, g = blockIdx.y, tid = threadIdx.x;
  const int t0 = g << 4;
  const float4* w24 = (const float4*)w2;    // row = 192 f4
  const float4* h1p4 = (const float4*)h1p;  // row = 64 f4
  const float4* b14 = (const float4*)b1;
  {
    const int row = tid & 255, seg = tid >> 8;
    const float4* src = w24 + row * 192 + kc * 12 + seg * 6;
    #pragma unroll
    for (int m = 0; m < 6; ++m) wlds4[(seg * 6 + m) * 256 + row] = src[m];
  }
  if (tid < 72) {
    int r = tid >> 2, cg = tid & 3, tt = t0 - 1 + r;
    float4 s = make_float4(0.f, 0.f, 0.f, 0.f);
    if (tt >= 0 && tt < T_FRAMES) {
      s = b14[kc * 4 + cg];
      #pragma unroll
      for (int p = 0; p < 5; ++p) {
        float4 v = h1p4[((p << 8) + tt) * 64 + kc * 4 + cg];
        s.x += v.x; s.y += v.y; s.z += v.z; s.w += v.w;
      }
      s.x = fmaxf(s.x, 0.f); s.y = fmaxf(s.y, 0.f); s.z = fmaxf(s.z, 0.f); s.w = fmaxf(s.w, 0.f);
    }
    inlds4[tid] = s;
  }
  __syncthreads();
  const int c = tid & 255, fh = tid >> 8;
  float acc[8] = {0.f, 0.f, 0.f, 0.f, 0.f, 0.f, 0.f, 0.f};
  conv_inner(wlds4, inlds4, c, fh, acc);
  const int ob = kc << 8;
  #pragma unroll
  for (int j = 0; j < 8; ++j) h2p[(ob + t0 + fh * 8 + j) * CCH + c] = acc[j];
}

// ---- K3: conv3 partials. grid (16 kc, 16 g). input h2 = relu(b2 + sum16 h2p), parallel-staged.
//      Writes ccpt[(t*222+cq)*16+kc] (transposed) for vectorized sum in fftltv ----
__global__ __launch_bounds__(512) void conv3_k(const float* __restrict__ h2p, const float* __restrict__ b2,
                                               const float* __restrict__ w3, float* __restrict__ ccpt) {
  __shared__ float4 wlds4[12 * 256];
  __shared__ float4 sred4[512 + 64];  // 9.2 KB
  __shared__ float4 inlds4[18 * 4];
  const int kc = blockIdx.x, g = blockIdx.y, tid = threadIdx.x;
  const int t0 = g << 4;
  const float4* w34 = (const float4*)w3;    // row = 192 f4
  const float4* h2p4 = (const float4*)h2p;  // row = 64 f4
  const float4* b24 = (const float4*)b2;
  {
    const int row = tid & 255, seg = tid >> 8;
    if (row < CCEP) {
      const float4* src = w34 + row * 192 + kc * 12 + seg * 6;
      #pragma unroll
      for (int m = 0; m < 6; ++m) wlds4[(seg * 6 + m) * 256 + row] = src[m];
    }
  }
  // parallel partial-sum staging: entry e (r,cg) x 8 pp-slots, each sums partials pp and pp+8
  {
    int e = tid >> 3, pp = tid & 7;
    int r = e >> 2, cg = e & 3, tt = t0 - 1 + r;
    float4 v = make_float4(0.f, 0.f, 0.f, 0.f);
    if (tt >= 0 && tt < T_FRAMES) {
      float4 a = h2p4[((pp << 8) + tt) * 64 + kc * 4 + cg];
      float4 b = h2p4[(((pp + 8) << 8) + tt) * 64 + kc * 4 + cg];
      v = make_float4(a.x + b.x, a.y + b.y, a.z + b.z, a.w + b.w);
    }
    sred4[tid] = v;
    if (tid < 64) {
      int e2 = 64 + (tid >> 3), pp2 = tid & 7;
      int r2 = e2 >> 2, cg2 = e2 & 3, tt2 = t0 - 1 + r2;
      float4 v2 = make_float4(0.f, 0.f, 0.f, 0.f);
      if (tt2 >= 0 && tt2 < T_FRAMES) {
        float4 a = h2p4[((pp2 << 8) + tt2) * 64 + kc * 4 + cg2];
        float4 b = h2p4[(((pp2 + 8) << 8) + tt2) * 64 + kc * 4 + cg2];
        v2 = make_float4(a.x + b.x, a.y + b.y, a.z + b.z, a.w + b.w);
      }
      sred4[512 + tid] = v2;
    }
  }
  __syncthreads();
  if (tid < 72) {
    int r = tid >> 2, cg = tid & 3, tt = t0 - 1 + r;
    float4 s = make_float4(0.f, 0.f, 0.f, 0.f);
    if (tt >= 0 && tt < T_FRAMES) {
      s = b24[kc * 4 + cg];
      const float4* src = (tid < 64) ? &sred4[tid * 8] : &sred4[512 + (tid - 64) * 8];
      #pragma unroll
      for (int pp = 0; pp < 8; ++pp) {
        float4 v = src[pp];
        s.x += v.x; s.y += v.y; s.z += v.z; s.w += v.w;
      }
      s.x = fmaxf(s.x, 0.f); s.y = fmaxf(s.y, 0.f); s.z = fmaxf(s.z, 0.f); s.w = fmaxf(s.w, 0.f);
    }
    inlds4[tid] = s;
  }
  __syncthreads();
  const int c = tid & 255, fh = tid >> 8;
  if (c < CCEP) {
    float acc[8] = {0.f, 0.f, 0.f, 0.f, 0.f, 0.f, 0.f, 0.f};
    conv_inner(wlds4, inlds4, c, fh, acc);
    #pragma unroll
    for (int j = 0; j < 8; ++j) ccpt[((t0 + fh * 8 + j) * CCEP + c) * 16 + kc] = acc[j];
  }
}

// ---- K4: fused spectral kernel (correlation theorem); ccpt sum via 4x float4 ----
__global__ __launch_bounds__(512) void fftltv_k(const float* __restrict__ ccpt, const float* __restrict__ b3,
                                                const float* __restrict__ quef, const float* __restrict__ z,
                                                const float* __restrict__ win, float* __restrict__ outw) {
  __shared__ float2 U[FFT_N];
  int t = blockIdx.x, tid = threadIdx.x;
  for (int i = tid; i < FFT_N; i += 512) {
    unsigned q = br10((unsigned)i);
    float a = 0.f, bv = 0.f;
    if (q >= 401u && q < 623u) {
      int cq = (int)(q - 401u);
      const float4* c4 = (const float4*)(ccpt + ((size_t)t * CCEP + cq) * 16);
      float4 s0 = c4[0], s1 = c4[1], s2 = c4[2], s3 = c4[3];
      float s = b3[cq] + s0.x + s0.y + s0.z + s0.w + s1.x + s1.y + s1.z + s1.w
                        + s2.x + s2.y + s2.z + s2.w + s3.x + s3.y + s3.z + s3.w;
      a = s / quef[cq];
    }
    if (q < 512u) {
      int idx = t * HOP + (int)q - 255;
      bv = (idx >= 0 && idx < ZLEN) ? z[idx] : 0.f;
    }
    U[i] = make_float2(a, bv);
  }
  __syncthreads();
  #pragma unroll
  for (int s = 1; s <= 10; ++s) {
    int half = 1 << (s - 1);
    int pos = tid & (half - 1);
    int i1 = ((tid >> (s - 1)) << s) + pos;
    int i2 = i1 + half;
    float ang = (-6.283185307179586f / (float)(1 << s)) * (float)pos;
    float sn, cs; __sincosf(ang, &sn, &cs);
    float2 v2 = U[i2], v1 = U[i1];
    float tr = cs * v2.x - sn * v2.y;
    float ti = cs * v2.y + sn * v2.x;
    U[i1] = make_float2(v1.x + tr, v1.y + ti);
    U[i2] = make_float2(v1.x - tr, v1.y - ti);
    __syncthreads();
  }
  {
    int j = tid;
    int mj = (FFT_N - j) & (FFT_N - 1);
    float2 Uj = U[j], Um = U[mj];
    float2 U5j = make_float2(0.f, 0.f);
    if (tid == 0) U5j = U[512];
    auto pcalc = [](float2 Uj, float2 Um) -> float2 {
      float Ar = 0.5f * (Uj.x + Um.x);
      float Ai = 0.5f * (Uj.y - Um.y);
      float Bx = 0.5f * (Uj.y + Um.y);
      float By = 0.5f * (Um.x - Uj.x);
      float mag = __expf(0.23025850929940457f * Ar);
      float sn, cs; __sincosf(Ai, &sn, &cs);
      float SPx = mag * cs, SPy = mag * sn;
      return make_float2(Bx * SPx + By * SPy, Bx * SPy - By * SPx);
    };
    float2 Pj = pcalc(Uj, Um);
    float2 P5 = (tid == 0) ? pcalc(U5j, U5j) : make_float2(0.f, 0.f);
    __syncthreads();
    U[j] = Pj;
    if (tid == 0) U[512] = P5;
    else U[mj] = make_float2(Pj.x, -Pj.y);
  }
  __syncthreads();
  #pragma unroll
  for (int s = 10; s >= 1; --s) {
    int half = 1 << (s - 1);
    int pos = tid & (half - 1);
    int i1 = ((tid >> (s - 1)) << s) + pos;
    int i2 = i1 + half;
    float ang = (6.283185307179586f / (float)(1 << s)) * (float)pos;
    float sn, cs; __sincosf(ang, &sn, &cs);
    float2 v1 = U[i1], v2 = U[i2];
    U[i1] = make_float2(v1.x + v2.x, v1.y + v2.y);
    float dr = v1.x - v2.x, di = v1.y - v2.y;
    U[i2] = make_float2(cs * dr - sn * di, cs * di + sn * dr);
    __syncthreads();
  }
  const float inv = 1.0f / (float)FFT_N;
  for (int i = tid; i < FFT_N; i += 512) {
    unsigned m = br10((unsigned)i);
    if (m < 512u) {
      int w = 511 - (int)m;
      outw[t * WINL + w] = U[i].x * inv * win[w];
    }
  }
}

// ---- K5: overlap-add (circular roll over t) + 128-tap postfilter ----
__global__ __launch_bounds__(256) void pf_k(const float* __restrict__ outw, const float* __restrict__ pf_w,
                                            const float* __restrict__ pf_b, float* __restrict__ y) {
  __shared__ float sb[256 + PF_KT - 1];
  __shared__ float wpf[PF_KT];
  int n0 = blockIdx.x * 256;
  for (int i = threadIdx.x; i < 256 + PF_KT - 1; i += 256) {
    int m = n0 - 63 + i;
    float v = 0.f;
    if (m >= 0 && m < ZLEN) {
      int t = m >> 8, j = m & 255;
      v = outw[t * WINL + j] + outw[((t - 1) & 255) * WINL + HOP + j];
    }
    sb[i] = v;
  }
  if (threadIdx.x < PF_KT) wpf[threadIdx.x] = pf_w[threadIdx.x];
  __syncthreads();
  float acc = pf_b[0];
  #pragma unroll 8
  for (int j = 0; j < PF_KT; ++j) acc += sb[threadIdx.x + j] * wpf[j];
  y[n0 + threadIdx.x] = acc;
}

extern "C" void kernel_launch(void* const* d_in, const int* in_sizes, int n_in,
                              void* d_out, int out_size, void* d_ws, size_t ws_size,
                              hipStream_t stream) {
  const float* x    = (const float*)d_in[0];
  const float* z    = (const float*)d_in[1];
  const float* w1   = (const float*)d_in[2];
  const float* b1   = (const float*)d_in[3];
  const float* w2   = (const float*)d_in[4];
  const float* b2   = (const float*)d_in[5];
  const float* w3   = (const float*)d_in[6];
  const float* b3   = (const float*)d_in[7];
  const float* pf_w = (const float*)d_in[8];
  const float* pf_b = (const float*)d_in[9];
  const float* quef = (const float*)d_in[10];
  const float* win  = (const float*)d_in[11];
  float* out = (float*)d_out;
  float* ws  = (float*)d_ws;

  // workspace layout (floats)
  float* h1p  = ws;                 // 5*256*256  = 327680
  float* h2p  = h1p + 327680;       // 16*256*256 = 1048576
  float* ccpt = h2p + 1048576;      // 256*222*16 = 909312 (transposed)
  float* outw = ccpt + 909312;      // 256*512    = 131072

  conv1_k<<<dim3(5, 16), 512, 0, stream>>>(x, w1, h1p);
  conv2_k<<<dim3(16, 16), 512, 0, stream>>>(h1p, b1, w2, h2p);
  conv3_k<<<dim3(16, 16), 512, 0, stream>>>(h2p, b2, w3, ccpt);
  fftltv_k<<<T_FRAMES, 512, 0, stream>>>(ccpt, b3, quef, z, win, outw);
  pf_k<<<ZLEN / 256, 256, 0, stream>>>(outw, pf_w, pf_b, out);
}

// Round 16
// 33.035 us; speedup vs baseline: 1.2418x; 1.2077x over previous
//
#include <hip/hip_runtime.h>

#define T_FRAMES 256
#define D_IN 80
#define CCH 256
#define CCEP 222
#define FFT_N 1024
#define HOP 256
#define WINL 512
#define PF_KT 128
#define ZLEN 65536

__device__ __forceinline__ unsigned br10(unsigned x) { return __brev(x) >> 22; }

// =============== shared conv inner loop (512 thr: c = tid&255, fh = tid>>8, 8 frames each) ===============
__device__ __forceinline__ void conv_inner(const float4* __restrict__ wlds4,
                                           const float4* __restrict__ inlds4,
                                           int c, int fh, float* __restrict__ acc) {
  #pragma unroll
  for (int cg = 0; cg < 4; ++cg) {
    float4 w0 = wlds4[(cg * 3 + 0) * 256 + c];
    float4 w1v = wlds4[(cg * 3 + 1) * 256 + c];
    float4 w2v = wlds4[(cg * 3 + 2) * 256 + c];
    float4 xr[10];
    #pragma unroll
    for (int r = 0; r < 10; ++r) xr[r] = inlds4[(fh * 8 + r) * 4 + cg];
    #pragma unroll
    for (int j = 0; j < 8; ++j) {
      float4 xa = xr[j], xb = xr[j + 1], xc = xr[j + 2];
      acc[j] += xa.x * w0.x  + xb.x * w0.y  + xc.x * w0.z
              + xa.y * w0.w  + xb.y * w1v.x + xc.y * w1v.y
              + xa.z * w1v.z + xb.z * w1v.w + xc.z * w2v.x
              + xa.w * w2v.y + xb.w * w2v.z + xc.w * w2v.w;
    }
  }
}

// ---- K_A: fused conv1+conv2. grid (16 kc, 16 g). Block computes h1 chunk [18 frames][16 ch]
//      in-LDS (no cross-block dep: conv2's cin chunk == conv1's out chunk), then conv2 partials ----
__global__ __launch_bounds__(512) void conv12_k(const float* __restrict__ x, const float* __restrict__ w1,
                                                const float* __restrict__ b1, const float* __restrict__ w2,
                                                float* __restrict__ h2p) {
  __shared__ float4 wlds4[12 * 256];   // w2 slice, 48 KB (R13 staging pattern)
  __shared__ float  w1lds[240 * 16];   // w1 slice transposed [j=cin*3+k][16 ch], 15 KB
  __shared__ float4 xlds4[20 * 20];    // x frames t0-2..t0+17, 6.4 KB
  __shared__ float4 inlds4[18 * 4];    // h1 chunk [18 frames][4 f4]
  const int kc = blockIdx.x, g = blockIdx.y, tid = threadIdx.x;
  const int t0 = g << 4;
  const float4* w24 = (const float4*)w2;  // row = 192 f4
  const float4* x4 = (const float4*)x;    // row = 20 f4
  #pragma unroll
  for (int it = 0; it < 6; ++it) {
    int idx = it * 512 + tid, cc = idx & 255, j4 = idx >> 8;
    wlds4[j4 * 256 + cc] = w24[cc * 192 + kc * 12 + j4];
  }
  for (int idx = tid; idx < 3840; idx += 512) {
    int ch = idx & 15, j = idx >> 4;
    w1lds[j * 16 + ch] = w1[(kc * 16 + ch) * 240 + j];
  }
  if (tid < 400) {
    int f = tid / 20, cg = tid - f * 20;
    int tt = t0 - 2 + f;
    xlds4[f * 20 + cg] = (tt >= 0 && tt < T_FRAMES) ? x4[tt * 20 + cg] : make_float4(0.f, 0.f, 0.f, 0.f);
  }
  __syncthreads();
  // inline conv1: 288 threads -> (f 0..17, ch 0..15); h1 frame tt = t0-1+f
  if (tid < 288) {
    int f = tid >> 4, ch = tid & 15;
    int tt = t0 - 1 + f;
    float acc = b1[kc * 16 + ch];
    const float* x0 = (const float*)&xlds4[(f + 0) * 20];
    const float* x1 = (const float*)&xlds4[(f + 1) * 20];
    const float* x2 = (const float*)&xlds4[(f + 2) * 20];
    #pragma unroll 8
    for (int cin = 0; cin < D_IN; ++cin) {
      acc += x0[cin] * w1lds[(cin * 3 + 0) * 16 + ch]
           + x1[cin] * w1lds[(cin * 3 + 1) * 16 + ch]
           + x2[cin] * w1lds[(cin * 3 + 2) * 16 + ch];
    }
    ((float*)inlds4)[f * 16 + ch] = (tt >= 0 && tt < T_FRAMES) ? fmaxf(acc, 0.f) : 0.f;
  }
  __syncthreads();
  const int c = tid & 255, fh = tid >> 8;
  float acc[8] = {0.f, 0.f, 0.f, 0.f, 0.f, 0.f, 0.f, 0.f};
  conv_inner(wlds4, inlds4, c, fh, acc);
  const int ob = kc << 8;
  #pragma unroll
  for (int j = 0; j < 8; ++j) h2p[(ob + t0 + fh * 8 + j) * CCH + c] = acc[j];
}

// ---- K_B: conv3 partials. grid (16 kc, 16 g). input h2 = relu(b2 + sum16 h2p) — R13 verbatim ----
__global__ __launch_bounds__(512) void conv3_k(const float* __restrict__ h2p, const float* __restrict__ b2,
                                               const float* __restrict__ w3, float* __restrict__ ccp) {
  __shared__ float4 wlds4[12 * 256];
  __shared__ float4 inlds4[18 * 4];
  const int kc = blockIdx.x, g = blockIdx.y, tid = threadIdx.x;
  const int t0 = g << 4;
  const float4* w34 = (const float4*)w3;    // row = 192 f4
  const float4* h2p4 = (const float4*)h2p;  // row = 64 f4
  const float4* b24 = (const float4*)b2;
  #pragma unroll
  for (int it = 0; it < 6; ++it) {
    int idx = it * 512 + tid, cc = idx & 255, j4 = idx >> 8;
    if (cc < CCEP) wlds4[j4 * 256 + cc] = w34[cc * 192 + kc * 12 + j4];
  }
  if (tid < 72) {
    int r = tid >> 2, cg = tid & 3, tt = t0 - 1 + r;
    float4 s = make_float4(0.f, 0.f, 0.f, 0.f);
    if (tt >= 0 && tt < T_FRAMES) {
      s = b24[kc * 4 + cg];
      #pragma unroll
      for (int p = 0; p < 16; ++p) {
        float4 v = h2p4[((p << 8) + tt) * 64 + kc * 4 + cg];
        s.x += v.x; s.y += v.y; s.z += v.z; s.w += v.w;
      }
      s.x = fmaxf(s.x, 0.f); s.y = fmaxf(s.y, 0.f); s.z = fmaxf(s.z, 0.f); s.w = fmaxf(s.w, 0.f);
    }
    inlds4[tid] = s;
  }
  __syncthreads();
  const int c = tid & 255, fh = tid >> 8;
  if (c < CCEP) {
    float acc[8] = {0.f, 0.f, 0.f, 0.f, 0.f, 0.f, 0.f, 0.f};
    conv_inner(wlds4, inlds4, c, fh, acc);
    const int ob = kc << 8;
    #pragma unroll
    for (int j = 0; j < 8; ++j) ccp[(ob + t0 + fh * 8 + j) * CCEP + c] = acc[j];
  }
}

// ---- K_C: fused spectral kernel (correlation theorem) — R13 verbatim ----
__global__ __launch_bounds__(512) void fftltv_k(const float* __restrict__ ccp, const float* __restrict__ b3,
                                                const float* __restrict__ quef, const float* __restrict__ z,
                                                const float* __restrict__ win, float* __restrict__ outw) {
  __shared__ float2 U[FFT_N];
  int t = blockIdx.x, tid = threadIdx.x;
  for (int i = tid; i < FFT_N; i += 512) {
    unsigned q = br10((unsigned)i);
    float a = 0.f, bv = 0.f;
    if (q >= 401u && q < 623u) {
      int cq = (int)(q - 401u);
      float s = b3[cq];
      #pragma unroll
      for (int p = 0; p < 16; ++p) s += ccp[((p << 8) + t) * CCEP + cq];
      a = s / quef[cq];
    }
    if (q < 512u) {
      int idx = t * HOP + (int)q - 255;
      bv = (idx >= 0 && idx < ZLEN) ? z[idx] : 0.f;
    }
    U[i] = make_float2(a, bv);
  }
  __syncthreads();
  #pragma unroll
  for (int s = 1; s <= 10; ++s) {
    int half = 1 << (s - 1);
    int pos = tid & (half - 1);
    int i1 = ((tid >> (s - 1)) << s) + pos;
    int i2 = i1 + half;
    float ang = (-6.283185307179586f / (float)(1 << s)) * (float)pos;
    float sn, cs; __sincosf(ang, &sn, &cs);
    float2 v2 = U[i2], v1 = U[i1];
    float tr = cs * v2.x - sn * v2.y;
    float ti = cs * v2.y + sn * v2.x;
    U[i1] = make_float2(v1.x + tr, v1.y + ti);
    U[i2] = make_float2(v1.x - tr, v1.y - ti);
    __syncthreads();
  }
  {
    int j = tid;
    int mj = (FFT_N - j) & (FFT_N - 1);
    float2 Uj = U[j], Um = U[mj];
    float2 U5j = make_float2(0.f, 0.f);
    if (tid == 0) U5j = U[512];
    auto pcalc = [](float2 Uj, float2 Um) -> float2 {
      float Ar = 0.5f * (Uj.x + Um.x);
      float Ai = 0.5f * (Uj.y - Um.y);
      float Bx = 0.5f * (Uj.y + Um.y);
      float By = 0.5f * (Um.x - Uj.x);
      float mag = __expf(0.23025850929940457f * Ar);
      float sn, cs; __sincosf(Ai, &sn, &cs);
      float SPx = mag * cs, SPy = mag * sn;
      return make_float2(Bx * SPx + By * SPy, Bx * SPy - By * SPx);
    };
    float2 Pj = pcalc(Uj, Um);
    float2 P5 = (tid == 0) ? pcalc(U5j, U5j) : make_float2(0.f, 0.f);
    __syncthreads();
    U[j] = Pj;
    if (tid == 0) U[512] = P5;
    else U[mj] = make_float2(Pj.x, -Pj.y);
  }
  __syncthreads();
  #pragma unroll
  for (int s = 10; s >= 1; --s) {
    int half = 1 << (s - 1);
    int pos = tid & (half - 1);
    int i1 = ((tid >> (s - 1)) << s) + pos;
    int i2 = i1 + half;
    float ang = (6.283185307179586f / (float)(1 << s)) * (float)pos;
    float sn, cs; __sincosf(ang, &sn, &cs);
    float2 v1 = U[i1], v2 = U[i2];
    U[i1] = make_float2(v1.x + v2.x, v1.y + v2.y);
    float dr = v1.x - v2.x, di = v1.y - v2.y;
    U[i2] = make_float2(cs * dr - sn * di, cs * di + sn * dr);
    __syncthreads();
  }
  const float inv = 1.0f / (float)FFT_N;
  for (int i = tid; i < FFT_N; i += 512) {
    unsigned m = br10((unsigned)i);
    if (m < 512u) {
      int w = 511 - (int)m;
      outw[t * WINL + w] = U[i].x * inv * win[w];
    }
  }
}

// ---- K_D: overlap-add (circular roll over t) + 128-tap postfilter — R13 verbatim ----
__global__ __launch_bounds__(256) void pf_k(const float* __restrict__ outw, const float* __restrict__ pf_w,
                                            const float* __restrict__ pf_b, float* __restrict__ y) {
  __shared__ float sb[256 + PF_KT - 1];
  __shared__ float wpf[PF_KT];
  int n0 = blockIdx.x * 256;
  for (int i = threadIdx.x; i < 256 + PF_KT - 1; i += 256) {
    int m = n0 - 63 + i;
    float v = 0.f;
    if (m >= 0 && m < ZLEN) {
      int t = m >> 8, j = m & 255;
      v = outw[t * WINL + j] + outw[((t - 1) & 255) * WINL + HOP + j];
    }
    sb[i] = v;
  }
  if (threadIdx.x < PF_KT) wpf[threadIdx.x] = pf_w[threadIdx.x];
  __syncthreads();
  float acc = pf_b[0];
  #pragma unroll 8
  for (int j = 0; j < PF_KT; ++j) acc += sb[threadIdx.x + j] * wpf[j];
  y[n0 + threadIdx.x] = acc;
}

extern "C" void kernel_launch(void* const* d_in, const int* in_sizes, int n_in,
                              void* d_out, int out_size, void* d_ws, size_t ws_size,
                              hipStream_t stream) {
  const float* x    = (const float*)d_in[0];
  const float* z    = (const float*)d_in[1];
  const float* w1   = (const float*)d_in[2];
  const float* b1   = (const float*)d_in[3];
  const float* w2   = (const float*)d_in[4];
  const float* b2   = (const float*)d_in[5];
  const float* w3   = (const float*)d_in[6];
  const float* b3   = (const float*)d_in[7];
  const float* pf_w = (const float*)d_in[8];
  const float* pf_b = (const float*)d_in[9];
  const float* quef = (const float*)d_in[10];
  const float* win  = (const float*)d_in[11];
  float* out = (float*)d_out;
  float* ws  = (float*)d_ws;

  // workspace layout (floats)
  float* h2p  = ws;                 // 16*256*256 = 1048576
  float* ccp  = h2p + 1048576;      // 16*256*222 = 909312
  float* outw = ccp + 909312;       // 256*512    = 131072

  conv12_k<<<dim3(16, 16), 512, 0, stream>>>(x, w1, b1, w2, h2p);
  conv3_k<<<dim3(16, 16), 512, 0, stream>>>(h2p, b2, w3, ccp);
  fftltv_k<<<T_FRAMES, 512, 0, stream>>>(ccp, b3, quef, z, win, outw);
  pf_k<<<ZLEN / 256, 256, 0, stream>>>(outw, pf_w, pf_b, out);
}

// Round 17
// 31.865 us; speedup vs baseline: 1.2874x; 1.0367x over previous
//
#include <hip/hip_runtime.h>

#define T_FRAMES 256
#define D_IN 80
#define CCH 256
#define CCEP 222
#define FFT_N 1024
#define HOP 256
#define WINL 512
#define PF_KT 128
#define ZLEN 65536

__device__ __forceinline__ unsigned br10(unsigned x) { return __brev(x) >> 22; }

// =============== shared conv inner loop (512 thr: c = tid&255, fh = tid>>8, 8 frames each) ===============
__device__ __forceinline__ void conv_inner(const float4* __restrict__ wlds4,
                                           const float4* __restrict__ inlds4,
                                           int c, int fh, float* __restrict__ acc) {
  #pragma unroll
  for (int cg = 0; cg < 4; ++cg) {
    float4 w0 = wlds4[(cg * 3 + 0) * 256 + c];
    float4 w1v = wlds4[(cg * 3 + 1) * 256 + c];
    float4 w2v = wlds4[(cg * 3 + 2) * 256 + c];
    float4 xr[10];
    #pragma unroll
    for (int r = 0; r < 10; ++r) xr[r] = inlds4[(fh * 8 + r) * 4 + cg];
    #pragma unroll
    for (int j = 0; j < 8; ++j) {
      float4 xa = xr[j], xb = xr[j + 1], xc = xr[j + 2];
      acc[j] += xa.x * w0.x  + xb.x * w0.y  + xc.x * w0.z
              + xa.y * w0.w  + xb.y * w1v.x + xc.y * w1v.y
              + xa.z * w1v.z + xb.z * w1v.w + xc.z * w2v.x
              + xa.w * w2v.y + xb.w * w2v.z + xc.w * w2v.w;
    }
  }
}

// ---- K_A: fused conv1+conv2. grid (16 kc, 16 g) — R16 verbatim ----
__global__ __launch_bounds__(512) void conv12_k(const float* __restrict__ x, const float* __restrict__ w1,
                                                const float* __restrict__ b1, const float* __restrict__ w2,
                                                float* __restrict__ h2p) {
  __shared__ float4 wlds4[12 * 256];   // w2 slice, 48 KB
  __shared__ float  w1lds[240 * 16];   // w1 slice transposed, 15 KB
  __shared__ float4 xlds4[20 * 20];    // x frames t0-2..t0+17
  __shared__ float4 inlds4[18 * 4];    // h1 chunk
  const int kc = blockIdx.x, g = blockIdx.y, tid = threadIdx.x;
  const int t0 = g << 4;
  const float4* w24 = (const float4*)w2;
  const float4* x4 = (const float4*)x;
  #pragma unroll
  for (int it = 0; it < 6; ++it) {
    int idx = it * 512 + tid, cc = idx & 255, j4 = idx >> 8;
    wlds4[j4 * 256 + cc] = w24[cc * 192 + kc * 12 + j4];
  }
  for (int idx = tid; idx < 3840; idx += 512) {
    int ch = idx & 15, j = idx >> 4;
    w1lds[j * 16 + ch] = w1[(kc * 16 + ch) * 240 + j];
  }
  if (tid < 400) {
    int f = tid / 20, cg = tid - f * 20;
    int tt = t0 - 2 + f;
    xlds4[f * 20 + cg] = (tt >= 0 && tt < T_FRAMES) ? x4[tt * 20 + cg] : make_float4(0.f, 0.f, 0.f, 0.f);
  }
  __syncthreads();
  if (tid < 288) {
    int f = tid >> 4, ch = tid & 15;
    int tt = t0 - 1 + f;
    float acc = b1[kc * 16 + ch];
    const float* x0 = (const float*)&xlds4[(f + 0) * 20];
    const float* x1 = (const float*)&xlds4[(f + 1) * 20];
    const float* x2 = (const float*)&xlds4[(f + 2) * 20];
    #pragma unroll 8
    for (int cin = 0; cin < D_IN; ++cin) {
      acc += x0[cin] * w1lds[(cin * 3 + 0) * 16 + ch]
           + x1[cin] * w1lds[(cin * 3 + 1) * 16 + ch]
           + x2[cin] * w1lds[(cin * 3 + 2) * 16 + ch];
    }
    ((float*)inlds4)[f * 16 + ch] = (tt >= 0 && tt < T_FRAMES) ? fmaxf(acc, 0.f) : 0.f;
  }
  __syncthreads();
  const int c = tid & 255, fh = tid >> 8;
  float acc[8] = {0.f, 0.f, 0.f, 0.f, 0.f, 0.f, 0.f, 0.f};
  conv_inner(wlds4, inlds4, c, fh, acc);
  const int ob = kc << 8;
  #pragma unroll
  for (int j = 0; j < 8; ++j) h2p[(ob + t0 + fh * 8 + j) * CCH + c] = acc[j];
}

// ---- K_B: conv3 partials. grid (16 kc, 16 g) — R13/R16 verbatim ----
__global__ __launch_bounds__(512) void conv3_k(const float* __restrict__ h2p, const float* __restrict__ b2,
                                               const float* __restrict__ w3, float* __restrict__ ccp) {
  __shared__ float4 wlds4[12 * 256];
  __shared__ float4 inlds4[18 * 4];
  const int kc = blockIdx.x, g = blockIdx.y, tid = threadIdx.x;
  const int t0 = g << 4;
  const float4* w34 = (const float4*)w3;
  const float4* h2p4 = (const float4*)h2p;
  const float4* b24 = (const float4*)b2;
  #pragma unroll
  for (int it = 0; it < 6; ++it) {
    int idx = it * 512 + tid, cc = idx & 255, j4 = idx >> 8;
    if (cc < CCEP) wlds4[j4 * 256 + cc] = w34[cc * 192 + kc * 12 + j4];
  }
  if (tid < 72) {
    int r = tid >> 2, cg = tid & 3, tt = t0 - 1 + r;
    float4 s = make_float4(0.f, 0.f, 0.f, 0.f);
    if (tt >= 0 && tt < T_FRAMES) {
      s = b24[kc * 4 + cg];
      #pragma unroll
      for (int p = 0; p < 16; ++p) {
        float4 v = h2p4[((p << 8) + tt) * 64 + kc * 4 + cg];
        s.x += v.x; s.y += v.y; s.z += v.z; s.w += v.w;
      }
      s.x = fmaxf(s.x, 0.f); s.y = fmaxf(s.y, 0.f); s.z = fmaxf(s.z, 0.f); s.w = fmaxf(s.w, 0.f);
    }
    inlds4[tid] = s;
  }
  __syncthreads();
  const int c = tid & 255, fh = tid >> 8;
  if (c < CCEP) {
    float acc[8] = {0.f, 0.f, 0.f, 0.f, 0.f, 0.f, 0.f, 0.f};
    conv_inner(wlds4, inlds4, c, fh, acc);
    const int ob = kc << 8;
    #pragma unroll
    for (int j = 0; j < 8; ++j) ccp[(ob + t0 + fh * 8 + j) * CCEP + c] = acc[j];
  }
}

// ---- K_C: fused spectral kernel. NEW: coalesced LDS-staged 16-partial reduction ----
__global__ __launch_bounds__(512) void fftltv_k(const float* __restrict__ ccp, const float* __restrict__ b3,
                                                const float* __restrict__ quef, const float* __restrict__ z,
                                                const float* __restrict__ win, float* __restrict__ outw) {
  __shared__ float2 U[FFT_N];
  __shared__ float ccs[224];
  int t = blockIdx.x, tid = threadIdx.x;
  // coalesced partial reduction: thread cq sums 16 partials (each p-slice read is 222 consecutive floats)
  if (tid < CCEP) {
    float s = b3[tid];
    #pragma unroll
    for (int p = 0; p < 16; ++p) s += ccp[((p << 8) + t) * CCEP + tid];
    ccs[tid] = s / quef[tid];
  }
  __syncthreads();
  for (int i = tid; i < FFT_N; i += 512) {
    unsigned q = br10((unsigned)i);
    float a = (q >= 401u && q < 623u) ? ccs[q - 401u] : 0.f;
    float bv = 0.f;
    if (q < 512u) {
      int idx = t * HOP + (int)q - 255;
      bv = (idx >= 0 && idx < ZLEN) ? z[idx] : 0.f;
    }
    U[i] = make_float2(a, bv);
  }
  __syncthreads();
  #pragma unroll
  for (int s = 1; s <= 10; ++s) {
    int half = 1 << (s - 1);
    int pos = tid & (half - 1);
    int i1 = ((tid >> (s - 1)) << s) + pos;
    int i2 = i1 + half;
    float ang = (-6.283185307179586f / (float)(1 << s)) * (float)pos;
    float sn, cs; __sincosf(ang, &sn, &cs);
    float2 v2 = U[i2], v1 = U[i1];
    float tr = cs * v2.x - sn * v2.y;
    float ti = cs * v2.y + sn * v2.x;
    U[i1] = make_float2(v1.x + tr, v1.y + ti);
    U[i2] = make_float2(v1.x - tr, v1.y - ti);
    __syncthreads();
  }
  {
    int j = tid;
    int mj = (FFT_N - j) & (FFT_N - 1);
    float2 Uj = U[j], Um = U[mj];
    float2 U5j = make_float2(0.f, 0.f);
    if (tid == 0) U5j = U[512];
    auto pcalc = [](float2 Uj, float2 Um) -> float2 {
      float Ar = 0.5f * (Uj.x + Um.x);
      float Ai = 0.5f * (Uj.y - Um.y);
      float Bx = 0.5f * (Uj.y + Um.y);
      float By = 0.5f * (Um.x - Uj.x);
      float mag = __expf(0.23025850929940457f * Ar);
      float sn, cs; __sincosf(Ai, &sn, &cs);
      float SPx = mag * cs, SPy = mag * sn;
      return make_float2(Bx * SPx + By * SPy, Bx * SPy - By * SPx);
    };
    float2 Pj = pcalc(Uj, Um);
    float2 P5 = (tid == 0) ? pcalc(U5j, U5j) : make_float2(0.f, 0.f);
    __syncthreads();
    U[j] = Pj;
    if (tid == 0) U[512] = P5;
    else U[mj] = make_float2(Pj.x, -Pj.y);
  }
  __syncthreads();
  #pragma unroll
  for (int s = 10; s >= 1; --s) {
    int half = 1 << (s - 1);
    int pos = tid & (half - 1);
    int i1 = ((tid >> (s - 1)) << s) + pos;
    int i2 = i1 + half;
    float ang = (6.283185307179586f / (float)(1 << s)) * (float)pos;
    float sn, cs; __sincosf(ang, &sn, &cs);
    float2 v1 = U[i1], v2 = U[i2];
    U[i1] = make_float2(v1.x + v2.x, v1.y + v2.y);
    float dr = v1.x - v2.x, di = v1.y - v2.y;
    U[i2] = make_float2(cs * dr - sn * di, cs * di + sn * dr);
    __syncthreads();
  }
  const float inv = 1.0f / (float)FFT_N;
  for (int i = tid; i < FFT_N; i += 512) {
    unsigned m = br10((unsigned)i);
    if (m < 512u) {
      int w = 511 - (int)m;
      outw[t * WINL + w] = U[i].x * inv * win[w];
    }
  }
}

// ---- K_D: overlap-add + 128-tap postfilter — verbatim ----
__global__ __launch_bounds__(256) void pf_k(const float* __restrict__ outw, const float* __restrict__ pf_w,
                                            const float* __restrict__ pf_b, float* __restrict__ y) {
  __shared__ float sb[256 + PF_KT - 1];
  __shared__ float wpf[PF_KT];
  int n0 = blockIdx.x * 256;
  for (int i = threadIdx.x; i < 256 + PF_KT - 1; i += 256) {
    int m = n0 - 63 + i;
    float v = 0.f;
    if (m >= 0 && m < ZLEN) {
      int t = m >> 8, j = m & 255;
      v = outw[t * WINL + j] + outw[((t - 1) & 255) * WINL + HOP + j];
    }
    sb[i] = v;
  }
  if (threadIdx.x < PF_KT) wpf[threadIdx.x] = pf_w[threadIdx.x];
  __syncthreads();
  float acc = pf_b[0];
  #pragma unroll 8
  for (int j = 0; j < PF_KT; ++j) acc += sb[threadIdx.x + j] * wpf[j];
  y[n0 + threadIdx.x] = acc;
}

extern "C" void kernel_launch(void* const* d_in, const int* in_sizes, int n_in,
                              void* d_out, int out_size, void* d_ws, size_t ws_size,
                              hipStream_t stream) {
  const float* x    = (const float*)d_in[0];
  const float* z    = (const float*)d_in[1];
  const float* w1   = (const float*)d_in[2];
  const float* b1   = (const float*)d_in[3];
  const float* w2   = (const float*)d_in[4];
  const float* b2   = (const float*)d_in[5];
  const float* w3   = (const float*)d_in[6];
  const float* b3   = (const float*)d_in[7];
  const float* pf_w = (const float*)d_in[8];
  const float* pf_b = (const float*)d_in[9];
  const float* quef = (const float*)d_in[10];
  const float* win  = (const float*)d_in[11];
  float* out = (float*)d_out;
  float* ws  = (float*)d_ws;

  // workspace layout (floats)
  float* h2p  = ws;                 // 16*256*256 = 1048576
  float* ccp  = h2p + 1048576;      // 16*256*222 = 909312
  float* outw = ccp + 909312;       // 256*512    = 131072

  conv12_k<<<dim3(16, 16), 512, 0, stream>>>(x, w1, b1, w2, h2p);
  conv3_k<<<dim3(16, 16), 512, 0, stream>>>(h2p, b2, w3, ccp);
  fftltv_k<<<T_FRAMES, 512, 0, stream>>>(ccp, b3, quef, z, win, outw);
  pf_k<<<ZLEN / 256, 256, 0, stream>>>(outw, pf_w, pf_b, out);
}